// Round 4
// baseline (1127.199 us; speedup 1.0000x reference)
//
#include <hip/hip_runtime.h>
#include <hip/hip_bf16.h>

// ValueNet: 7x SAGEConv(mean) + global_add_pool + MLP head.
// N=50000 nodes, E=600000 edges/set, H=128, G=64 graphs. All fp32.

constexpr int N_NODES = 50000;
constexpr int NE      = 600000;
constexpr int H       = 128;
constexpr int NG      = 64;

// ---------------- CSR build (counting sort by dst) ----------------

__global__ void k_count(const int* __restrict__ dst, int* __restrict__ cnt) {
    int e = blockIdx.x * blockDim.x + threadIdx.x;
    if (e < NE) atomicAdd(&cnt[dst[e]], 1);
}

constexpr int SCAN_B = 256;
constexpr int SCAN_G = (N_NODES + SCAN_B - 1) / SCAN_B;  // 196

__global__ void k_bsum(const int* __restrict__ cnt, int* __restrict__ bsum) {
    __shared__ int sh[SCAN_B];
    int t = threadIdx.x;
    int i = blockIdx.x * SCAN_B + t;
    sh[t] = (i < N_NODES) ? cnt[i] : 0;
    __syncthreads();
    for (int off = SCAN_B / 2; off > 0; off >>= 1) {
        if (t < off) sh[t] += sh[t + off];
        __syncthreads();
    }
    if (t == 0) bsum[blockIdx.x] = sh[0];
}

__global__ void k_bscan(int* bsum, int* ptr) {  // 1 block
    __shared__ int sh[SCAN_B];
    int t = threadIdx.x;
    int v = (t < SCAN_G) ? bsum[t] : 0;
    sh[t] = v;
    __syncthreads();
    for (int off = 1; off < SCAN_B; off <<= 1) {
        int u = (t >= off) ? sh[t - off] : 0;
        __syncthreads();
        if (t >= off) sh[t] += u;
        __syncthreads();
    }
    if (t < SCAN_G) bsum[t] = sh[t] - v;
    if (t == 0) ptr[N_NODES] = sh[SCAN_B - 1];
}

__global__ void k_bwrite(const int* cnt, const int* __restrict__ boff,
                         int* __restrict__ ptr, int* fill) {
    __shared__ int sh[SCAN_B];
    int t = threadIdx.x;
    int i = blockIdx.x * SCAN_B + t;
    int v = (i < N_NODES) ? cnt[i] : 0;
    sh[t] = v;
    __syncthreads();
    for (int off = 1; off < SCAN_B; off <<= 1) {
        int u = (t >= off) ? sh[t - off] : 0;
        __syncthreads();
        if (t >= off) sh[t] += u;
        __syncthreads();
    }
    int excl = sh[t] - v + boff[blockIdx.x];
    if (i < N_NODES) {
        ptr[i]  = excl;
        fill[i] = excl;
    }
}

__global__ void k_build(const int* __restrict__ src, const int* __restrict__ dst,
                        int* __restrict__ fill, int* __restrict__ adj) {
    int e = blockIdx.x * blockDim.x + threadIdx.x;
    if (e < NE) {
        int pos = atomicAdd(&fill[dst[e]], 1);
        adj[pos] = src[e];
    }
}

// ---------------- mean aggregation ----------------
// One wave = 2 nodes (32 lanes each, float4/lane = full 512B row).
// Neighbor idx preloaded 32-wide, broadcast via shfl; gather 8-wide ILP.

__global__ __launch_bounds__(256) void k_agg(const float* __restrict__ h,
                                             const int* __restrict__ ptr,
                                             const int* __restrict__ adj,
                                             float* __restrict__ agg) {
    int wid  = (blockIdx.x * blockDim.x + threadIdx.x) >> 6;
    int lane = threadIdx.x & 63;
    int sl   = lane & 31;
    int node = wid * 2 + (lane >> 5);
    if (node >= N_NODES) return;
    int beg = ptr[node], end = ptr[node + 1];
    int deg = end - beg;
    const float* hrow = h + sl * 4;
    float ax = 0.f, ay = 0.f, az = 0.f, aw = 0.f;
    for (int base = 0; base < deg; base += 32) {
        int m = deg - base;
        if (m > 32) m = 32;
        int idx = (sl < m) ? adj[beg + base + sl] : 0;
        int j = 0;
        for (; j + 8 <= m; j += 8) {
            int n0 = __shfl(idx, j,     32);
            int n1 = __shfl(idx, j + 1, 32);
            int n2 = __shfl(idx, j + 2, 32);
            int n3 = __shfl(idx, j + 3, 32);
            int n4 = __shfl(idx, j + 4, 32);
            int n5 = __shfl(idx, j + 5, 32);
            int n6 = __shfl(idx, j + 6, 32);
            int n7 = __shfl(idx, j + 7, 32);
            float4 v0 = *(const float4*)(hrow + (size_t)n0 * H);
            float4 v1 = *(const float4*)(hrow + (size_t)n1 * H);
            float4 v2 = *(const float4*)(hrow + (size_t)n2 * H);
            float4 v3 = *(const float4*)(hrow + (size_t)n3 * H);
            float4 v4 = *(const float4*)(hrow + (size_t)n4 * H);
            float4 v5 = *(const float4*)(hrow + (size_t)n5 * H);
            float4 v6 = *(const float4*)(hrow + (size_t)n6 * H);
            float4 v7 = *(const float4*)(hrow + (size_t)n7 * H);
            ax += ((v0.x + v1.x) + (v2.x + v3.x)) + ((v4.x + v5.x) + (v6.x + v7.x));
            ay += ((v0.y + v1.y) + (v2.y + v3.y)) + ((v4.y + v5.y) + (v6.y + v7.y));
            az += ((v0.z + v1.z) + (v2.z + v3.z)) + ((v4.z + v5.z) + (v6.z + v7.z));
            aw += ((v0.w + v1.w) + (v2.w + v3.w)) + ((v4.w + v5.w) + (v6.w + v7.w));
        }
        for (; j + 4 <= m; j += 4) {
            int n0 = __shfl(idx, j,     32);
            int n1 = __shfl(idx, j + 1, 32);
            int n2 = __shfl(idx, j + 2, 32);
            int n3 = __shfl(idx, j + 3, 32);
            float4 v0 = *(const float4*)(hrow + (size_t)n0 * H);
            float4 v1 = *(const float4*)(hrow + (size_t)n1 * H);
            float4 v2 = *(const float4*)(hrow + (size_t)n2 * H);
            float4 v3 = *(const float4*)(hrow + (size_t)n3 * H);
            ax += (v0.x + v1.x) + (v2.x + v3.x);
            ay += (v0.y + v1.y) + (v2.y + v3.y);
            az += (v0.z + v1.z) + (v2.z + v3.z);
            aw += (v0.w + v1.w) + (v2.w + v3.w);
        }
        for (; j < m; ++j) {
            int n0 = __shfl(idx, j, 32);
            float4 v0 = *(const float4*)(hrow + (size_t)n0 * H);
            ax += v0.x; ay += v0.y; az += v0.z; aw += v0.w;
        }
    }
    float inv = 1.0f / (float)(deg > 1 ? deg : 1);
    *(float4*)(agg + (size_t)node * H + sl * 4) =
        make_float4(ax * inv, ay * inv, az * inv, aw * inv);
}

// ---------------- fused SAGE GEMM ----------------
// out = [agg, x] @ [Wl; Wr] + bl  (flattened K=256), optional L2-norm.
// Block 128 thr (2 waves), tile 64x128, per-thread 8 rows x (4+4) split cols.
// Split-column microtile: 16 lanes stride 16B -> every bank 2x (free).
// LDS double-buffered: ONE barrier per K-tile; global prefetch 2 tiles ahead.

constexpr int BM = 64;
constexpr int KB = 8;

__global__ __launch_bounds__(128) void k_gemm(const float* __restrict__ Aagg,
                                              const float* __restrict__ Ax,
                                              const float* __restrict__ Wl,
                                              const float* __restrict__ Wr,
                                              const float* __restrict__ bl,
                                              float* __restrict__ out, int norm) {
    __shared__ float Ash[2][KB][BM + 4];   // 68-float rows
    __shared__ float Wsh[2][KB][H];

    int tid = threadIdx.x;
    int tc  = tid & 15;   // cols tc*4..+3 and 64+tc*4..+3
    int tr  = tid >> 4;   // rows tr*8..+7
    int rowBase = blockIdx.x * BM;

    float acc[8][8];
#pragma unroll
    for (int i = 0; i < 8; ++i)
#pragma unroll
        for (int j = 0; j < 8; ++j) acc[i][j] = 0.f;

    int lr = tid >> 1;        // 0..63  A-load row
    int lk = (tid & 1) * 4;   // 0 or 4 A-load k quad
    int grow = rowBase + lr;
    if (grow > N_NODES - 1) grow = N_NODES - 1;
    int wk = tid >> 4;        // 0..7   W-load k
    int wc = (tid & 15) * 4;  // W-load col (x2: wc and wc+64)

    const float* Asel[2] = {Aagg, Ax};
    const float* Wsel[2] = {Wl, Wr};

    // tile 0 -> regs
    float4 ga  = *(const float4*)(Aagg + (size_t)grow * H + lk);
    float4 gw0 = *(const float4*)(Wl + (size_t)wk * H + wc);
    float4 gw1 = *(const float4*)(Wl + (size_t)wk * H + wc + 64);
    // store tile 0 into buf 0
    Ash[0][lk][lr]     = ga.x;
    Ash[0][lk + 1][lr] = ga.y;
    Ash[0][lk + 2][lr] = ga.z;
    Ash[0][lk + 3][lr] = ga.w;
    *(float4*)&Wsh[0][wk][wc]      = gw0;
    *(float4*)&Wsh[0][wk][wc + 64] = gw1;
    // prefetch tile 1 -> regs
    {
        const float* A = Asel[KB >> 7];
        const float* W = Wsel[KB >> 7];
        int ko = KB & (H - 1);
        ga  = *(const float4*)(A + (size_t)grow * H + ko + lk);
        gw0 = *(const float4*)(W + (size_t)(ko + wk) * H + wc);
        gw1 = *(const float4*)(W + (size_t)(ko + wk) * H + wc + 64);
    }

    int cur = 0;
    for (int kt = 0; kt < 2 * H; kt += KB) {
        __syncthreads();   // buf[cur] ready; buf[cur^1] fully consumed
        int kn = kt + KB;
        if (kn < 2 * H) {
            int nb = cur ^ 1;
            Ash[nb][lk][lr]     = ga.x;
            Ash[nb][lk + 1][lr] = ga.y;
            Ash[nb][lk + 2][lr] = ga.z;
            Ash[nb][lk + 3][lr] = ga.w;
            *(float4*)&Wsh[nb][wk][wc]      = gw0;
            *(float4*)&Wsh[nb][wk][wc + 64] = gw1;
            int k2 = kn + KB;
            if (k2 < 2 * H) {
                const float* A = Asel[k2 >> 7];
                const float* W = Wsel[k2 >> 7];
                int ko = k2 & (H - 1);
                ga  = *(const float4*)(A + (size_t)grow * H + ko + lk);
                gw0 = *(const float4*)(W + (size_t)(ko + wk) * H + wc);
                gw1 = *(const float4*)(W + (size_t)(ko + wk) * H + wc + 64);
            }
        }
#pragma unroll
        for (int kk = 0; kk < KB; ++kk) {
            float4 a0 = *(const float4*)&Ash[cur][kk][tr * 8];
            float4 a1 = *(const float4*)&Ash[cur][kk][tr * 8 + 4];
            float4 w0 = *(const float4*)&Wsh[cur][kk][tc * 4];
            float4 w1 = *(const float4*)&Wsh[cur][kk][tc * 4 + 64];
            float av[8] = {a0.x, a0.y, a0.z, a0.w, a1.x, a1.y, a1.z, a1.w};
            float wv[8] = {w0.x, w0.y, w0.z, w0.w, w1.x, w1.y, w1.z, w1.w};
#pragma unroll
            for (int i = 0; i < 8; ++i)
#pragma unroll
                for (int j = 0; j < 8; ++j) acc[i][j] += av[i] * wv[j];
        }
        cur ^= 1;
    }

    float bv[8];
#pragma unroll
    for (int j = 0; j < 4; ++j) {
        bv[j]     = bl[tc * 4 + j];
        bv[j + 4] = bl[64 + tc * 4 + j];
    }
#pragma unroll
    for (int i = 0; i < 8; ++i)
#pragma unroll
        for (int j = 0; j < 8; ++j) acc[i][j] += bv[j];

    if (norm) {
#pragma unroll
        for (int i = 0; i < 8; ++i) {
            float ss = 0.f;
#pragma unroll
            for (int j = 0; j < 8; ++j) ss += acc[i][j] * acc[i][j];
#pragma unroll
            for (int m = 1; m < 16; m <<= 1) ss += __shfl_xor(ss, m, 16);
            float inv = 1.0f / fmaxf(sqrtf(ss), 1e-12f);
#pragma unroll
            for (int j = 0; j < 8; ++j) acc[i][j] *= inv;
        }
    }

#pragma unroll
    for (int i = 0; i < 8; ++i) {
        int r = rowBase + tr * 8 + i;
        if (r < N_NODES) {
            *(float4*)(out + (size_t)r * H + tc * 4) =
                make_float4(acc[i][0], acc[i][1], acc[i][2], acc[i][3]);
            *(float4*)(out + (size_t)r * H + tc * 4 + 64) =
                make_float4(acc[i][4], acc[i][5], acc[i][6], acc[i][7]);
        }
    }
}

// ---------------- global add pool (batch sorted) ----------------

constexpr int POOL_ROWS = 64;

__global__ void k_pool(const float* __restrict__ h, const int* __restrict__ batch,
                       float* __restrict__ g) {
    int col = threadIdx.x;  // 0..127
    int r0 = blockIdx.x * POOL_ROWS;
    int r1 = r0 + POOL_ROWS;
    if (r1 > N_NODES) r1 = N_NODES;
    if (r0 >= N_NODES) return;
    float acc = 0.f;
    int cur = batch[r0];
    int r = r0;
    for (; r + 4 <= r1; r += 4) {
        float v0 = h[(size_t)r * H + col];
        float v1 = h[(size_t)(r + 1) * H + col];
        float v2 = h[(size_t)(r + 2) * H + col];
        float v3 = h[(size_t)(r + 3) * H + col];
        int b3 = batch[r + 3];
        if (b3 == cur) {
            acc += (v0 + v1) + (v2 + v3);
        } else {
            int b0 = batch[r], b1 = batch[r + 1], b2 = batch[r + 2];
            if (b0 != cur) { atomicAdd(&g[cur * H + col], acc); acc = 0.f; cur = b0; }
            acc += v0;
            if (b1 != cur) { atomicAdd(&g[cur * H + col], acc); acc = 0.f; cur = b1; }
            acc += v1;
            if (b2 != cur) { atomicAdd(&g[cur * H + col], acc); acc = 0.f; cur = b2; }
            acc += v2;
            if (b3 != cur) { atomicAdd(&g[cur * H + col], acc); acc = 0.f; cur = b3; }
            acc += v3;
        }
    }
    for (; r < r1; ++r) {
        int b = batch[r];
        if (b != cur) { atomicAdd(&g[cur * H + col], acc); acc = 0.f; cur = b; }
        acc += h[(size_t)r * H + col];
    }
    atomicAdd(&g[cur * H + col], acc);
}

// ---------------- MLP head ----------------

__global__ void k_mlp(const float* __restrict__ g, const float* __restrict__ W0,
                      const float* __restrict__ b0, const float* __restrict__ W1,
                      const float* __restrict__ b1, const float* __restrict__ Wh,
                      const float* __restrict__ bh, float* __restrict__ out) {
    int gi = blockIdx.x;
    int t  = threadIdx.x;  // 0..127
    __shared__ float buf0[H];
    __shared__ float buf1[H];
    __shared__ float red[2];

    float acc = b0[t];
    for (int k = 0; k < H; ++k) acc += g[gi * H + k] * W0[k * H + t];
    buf0[t] = fmaxf(acc, 0.f);
    __syncthreads();

    acc = b1[t];
    for (int k = 0; k < H; ++k) acc += buf0[k] * W1[k * H + t];
    buf1[t] = fmaxf(acc, 0.f);
    __syncthreads();

    float p = buf1[t] * Wh[t];
    for (int m = 1; m < 64; m <<= 1) p += __shfl_xor(p, m, 64);
    if ((t & 63) == 0) red[t >> 6] = p;
    __syncthreads();
    if (t == 0) out[gi] = red[0] + red[1] + bh[0];
}

// ---------------- driver ----------------

extern "C" void kernel_launch(void* const* d_in, const int* in_sizes, int n_in,
                              void* d_out, int out_size, void* d_ws, size_t ws_size,
                              hipStream_t stream) {
    const float* x     = (const float*)d_in[0];
    const int*   eic   = (const int*)d_in[1];
    const int*   eid   = (const int*)d_in[2];
    const int*   eit   = (const int*)d_in[3];
    const int*   batch = (const int*)d_in[4];
    const float* cW[5][3];
    for (int c = 0; c < 5; ++c) {
        cW[c][0] = (const float*)d_in[5 + c * 3 + 0];  // Wl
        cW[c][1] = (const float*)d_in[5 + c * 3 + 1];  // bl
        cW[c][2] = (const float*)d_in[5 + c * 3 + 2];  // Wr
    }
    const float* l0_W = (const float*)d_in[20];
    const float* l0_b = (const float*)d_in[21];
    const float* l1_W = (const float*)d_in[22];
    const float* l1_b = (const float*)d_in[23];
    const float* hd_W = (const float*)d_in[24];
    const float* hd_b = (const float*)d_in[25];
    float* outp = (float*)d_out;

    const size_t NH = (size_t)N_NODES * H;
    float* bufA = (float*)d_ws;
    float* bufB = bufA + NH;
    float* aggb = bufB + NH;
    float* gbuf = aggb + NH;
    int* iws  = (int*)(gbuf + (size_t)NG * H);
    int* ptr0 = iws;
    int* ptr1 = ptr0 + (N_NODES + 1);
    int* ptr2 = ptr1 + (N_NODES + 1);
    int* adj0 = ptr2 + (N_NODES + 1);
    int* adj1 = adj0 + NE;
    int* adj2 = adj1 + NE;
    int* fill = adj2 + NE;
    int* bsum = fill + N_NODES;

    const int* esrc[3] = {eic, eid, eit};
    int* ptrs[3] = {ptr0, ptr1, ptr2};
    int* adjs[3] = {adj0, adj1, adj2};

    dim3 b256(256);
    dim3 gE((NE + 255) / 256);

    for (int s = 0; s < 3; ++s) {
        hipMemsetAsync(fill, 0, N_NODES * sizeof(int), stream);
        k_count<<<gE, b256, 0, stream>>>(esrc[s] + NE, fill);
        k_bsum<<<dim3(SCAN_G), b256, 0, stream>>>(fill, bsum);
        k_bscan<<<dim3(1), b256, 0, stream>>>(bsum, ptrs[s]);
        k_bwrite<<<dim3(SCAN_G), b256, 0, stream>>>(fill, bsum, ptrs[s], fill);
        k_build<<<gE, b256, 0, stream>>>(esrc[s], esrc[s] + NE, fill, adjs[s]);
    }

    const int L_set[7]  = {1, 0, 0, 2, 1, 0, 0};
    const int L_conv[7] = {0, 1, 1, 2, 3, 4, 4};
    const int L_norm[7] = {1, 1, 1, 0, 1, 1, 1};

    int nWaves = (N_NODES + 1) / 2;
    dim3 gAgg((nWaves + 3) / 4);
    dim3 gGemm((N_NODES + BM - 1) / BM);   // 782 blocks of 128 thr

    const float* hin = x;
    float* bufs[2] = {bufA, bufB};
    for (int L = 0; L < 7; ++L) {
        float* hout = bufs[L & 1];
        int s = L_set[L], c = L_conv[L];
        k_agg<<<gAgg, b256, 0, stream>>>(hin, ptrs[s], adjs[s], aggb);
        k_gemm<<<gGemm, dim3(128), 0, stream>>>(aggb, hin, cW[c][0], cW[c][2],
                                                cW[c][1], hout, L_norm[L]);
        hin = hout;
    }

    hipMemsetAsync(gbuf, 0, (size_t)NG * H * sizeof(float), stream);
    k_pool<<<dim3((N_NODES + POOL_ROWS - 1) / POOL_ROWS), dim3(H), 0, stream>>>(
        hin, batch, gbuf);
    k_mlp<<<dim3(NG), dim3(H), 0, stream>>>(gbuf, l0_W, l0_b, l1_W, l1_b, hd_W, hd_b,
                                            outp);
}

// Round 5
// 1071.250 us; speedup vs baseline: 1.0522x; 1.0522x over previous
//
#include <hip/hip_runtime.h>
#include <hip/hip_bf16.h>

// ValueNet: 7x SAGEConv(mean) + global_add_pool + MLP head.
// N=50000 nodes, E=600000 edges/set, H=128, G=64 graphs. All fp32.
//
// Layer reformulation (linearity of mean):
//   out_i = mean_j(h_j) @ Wl + bl + h_i @ Wr
//         = mean_j(z_j) + bl + y_i,  where z = h@Wl, y = h@Wr.
// So per layer: ONE dense GEMM pass h -> (z,y), then a gather kernel that
// aggregates z, adds bl + y, and applies the optional L2-norm.

constexpr int N_NODES = 50000;
constexpr int NE      = 600000;
constexpr int H       = 128;
constexpr int NG      = 64;

// ---------------- CSR build (counting sort by dst) ----------------

__global__ void k_count(const int* __restrict__ dst, int* __restrict__ cnt) {
    int e = blockIdx.x * blockDim.x + threadIdx.x;
    if (e < NE) atomicAdd(&cnt[dst[e]], 1);
}

constexpr int SCAN_B = 256;
constexpr int SCAN_G = (N_NODES + SCAN_B - 1) / SCAN_B;  // 196

__global__ void k_bsum(const int* __restrict__ cnt, int* __restrict__ bsum) {
    __shared__ int sh[SCAN_B];
    int t = threadIdx.x;
    int i = blockIdx.x * SCAN_B + t;
    sh[t] = (i < N_NODES) ? cnt[i] : 0;
    __syncthreads();
    for (int off = SCAN_B / 2; off > 0; off >>= 1) {
        if (t < off) sh[t] += sh[t + off];
        __syncthreads();
    }
    if (t == 0) bsum[blockIdx.x] = sh[0];
}

__global__ void k_bscan(int* bsum, int* ptr) {  // 1 block
    __shared__ int sh[SCAN_B];
    int t = threadIdx.x;
    int v = (t < SCAN_G) ? bsum[t] : 0;
    sh[t] = v;
    __syncthreads();
    for (int off = 1; off < SCAN_B; off <<= 1) {
        int u = (t >= off) ? sh[t - off] : 0;
        __syncthreads();
        if (t >= off) sh[t] += u;
        __syncthreads();
    }
    if (t < SCAN_G) bsum[t] = sh[t] - v;
    if (t == 0) ptr[N_NODES] = sh[SCAN_B - 1];
}

__global__ void k_bwrite(const int* cnt, const int* __restrict__ boff,
                         int* __restrict__ ptr, int* fill) {
    __shared__ int sh[SCAN_B];
    int t = threadIdx.x;
    int i = blockIdx.x * SCAN_B + t;
    int v = (i < N_NODES) ? cnt[i] : 0;
    sh[t] = v;
    __syncthreads();
    for (int off = 1; off < SCAN_B; off <<= 1) {
        int u = (t >= off) ? sh[t - off] : 0;
        __syncthreads();
        if (t >= off) sh[t] += u;
        __syncthreads();
    }
    int excl = sh[t] - v + boff[blockIdx.x];
    if (i < N_NODES) {
        ptr[i]  = excl;
        fill[i] = excl;
    }
}

__global__ void k_build(const int* __restrict__ src, const int* __restrict__ dst,
                        int* __restrict__ fill, int* __restrict__ adj) {
    int e = blockIdx.x * blockDim.x + threadIdx.x;
    if (e < NE) {
        int pos = atomicAdd(&fill[dst[e]], 1);
        adj[pos] = src[e];
    }
}

// ---------------- dense GEMM: (z,y) = h @ (Wl, Wr) ----------------
// Block 256 thr (4 waves), tile 64 rows x 256 cols (z:128 | y:128).
// Per-thread 4 rows x 16 cols. Double-buffered LDS, one barrier per K-tile.
// LDS reads: A broadcast (16 lanes same addr), W 2-way (free).

constexpr int BM = 64;
constexpr int KB = 8;
constexpr int BN = 2 * H;  // 256

__global__ __launch_bounds__(256) void k_gemm(const float* __restrict__ A,
                                              const float* __restrict__ Wl,
                                              const float* __restrict__ Wr,
                                              float* __restrict__ z,
                                              float* __restrict__ y) {
    __shared__ float Ash[2][KB][BM + 4];
    __shared__ float Wsh[2][KB][BN];

    int tid = threadIdx.x;
    int tc  = tid & 15;   // col group: tc*4 in each of 4 regions (0,64,128,192)
    int tr  = tid >> 4;   // 0..15, rows tr*4..+3
    int rowBase = blockIdx.x * BM;

    float acc[4][16];
#pragma unroll
    for (int i = 0; i < 4; ++i)
#pragma unroll
        for (int j = 0; j < 16; ++j) acc[i][j] = 0.f;

    int lr = tid & 63;          // A-load row
    int lk = (tid >> 6) * 2;    // 0,2,4,6 A-load k pair
    int grow = rowBase + lr;
    if (grow > N_NODES - 1) grow = N_NODES - 1;
    int wk = tid >> 5;          // 0..7 W-load k
    int wc = (tid & 31) * 4;    // 0..124 W-load col

    // tile 0 -> regs -> LDS buf 0
    float2 ga = *(const float2*)(A + (size_t)grow * H + lk);
    float4 gl = *(const float4*)(Wl + (size_t)wk * H + wc);
    float4 gr = *(const float4*)(Wr + (size_t)wk * H + wc);
    Ash[0][lk][lr]     = ga.x;
    Ash[0][lk + 1][lr] = ga.y;
    *(float4*)&Wsh[0][wk][wc]     = gl;
    *(float4*)&Wsh[0][wk][wc + H] = gr;
    // prefetch tile 1 -> regs
    ga = *(const float2*)(A + (size_t)grow * H + KB + lk);
    gl = *(const float4*)(Wl + (size_t)(KB + wk) * H + wc);
    gr = *(const float4*)(Wr + (size_t)(KB + wk) * H + wc);

    int cur = 0;
    for (int kt = 0; kt < H; kt += KB) {
        __syncthreads();
        int kn = kt + KB;
        if (kn < H) {
            int nb = cur ^ 1;
            Ash[nb][lk][lr]     = ga.x;
            Ash[nb][lk + 1][lr] = ga.y;
            *(float4*)&Wsh[nb][wk][wc]     = gl;
            *(float4*)&Wsh[nb][wk][wc + H] = gr;
            int k2 = kn + KB;
            if (k2 < H) {
                ga = *(const float2*)(A + (size_t)grow * H + k2 + lk);
                gl = *(const float4*)(Wl + (size_t)(k2 + wk) * H + wc);
                gr = *(const float4*)(Wr + (size_t)(k2 + wk) * H + wc);
            }
        }
#pragma unroll
        for (int kk = 0; kk < KB; ++kk) {
            float4 a  = *(const float4*)&Ash[cur][kk][tr * 4];
            float4 w0 = *(const float4*)&Wsh[cur][kk][tc * 4];
            float4 w1 = *(const float4*)&Wsh[cur][kk][tc * 4 + 64];
            float4 w2 = *(const float4*)&Wsh[cur][kk][tc * 4 + 128];
            float4 w3 = *(const float4*)&Wsh[cur][kk][tc * 4 + 192];
            float av[4] = {a.x, a.y, a.z, a.w};
            float wv[16] = {w0.x, w0.y, w0.z, w0.w, w1.x, w1.y, w1.z, w1.w,
                            w2.x, w2.y, w2.z, w2.w, w3.x, w3.y, w3.z, w3.w};
#pragma unroll
            for (int i = 0; i < 4; ++i)
#pragma unroll
                for (int j = 0; j < 16; ++j) acc[i][j] += av[i] * wv[j];
        }
        cur ^= 1;
    }

#pragma unroll
    for (int i = 0; i < 4; ++i) {
        int r = rowBase + tr * 4 + i;
        if (r < N_NODES) {
            *(float4*)(z + (size_t)r * H + tc * 4) =
                make_float4(acc[i][0], acc[i][1], acc[i][2], acc[i][3]);
            *(float4*)(z + (size_t)r * H + tc * 4 + 64) =
                make_float4(acc[i][4], acc[i][5], acc[i][6], acc[i][7]);
            *(float4*)(y + (size_t)r * H + tc * 4) =
                make_float4(acc[i][8], acc[i][9], acc[i][10], acc[i][11]);
            *(float4*)(y + (size_t)r * H + tc * 4 + 64) =
                make_float4(acc[i][12], acc[i][13], acc[i][14], acc[i][15]);
        }
    }
}

// ---------------- gather + epilogue: h_i = norm(mean_j z_j + bl + y_i) ----------------
// One 32-lane half-wave per node, float4/lane = full 512B row.
// Neighbor idx preloaded 32-wide, broadcast via shfl; gather 8-wide ILP.

__global__ __launch_bounds__(256) void k_aggnorm(const float* __restrict__ z,
                                                 const float* __restrict__ y,
                                                 const int* __restrict__ ptr,
                                                 const int* __restrict__ adj,
                                                 const float* __restrict__ bl,
                                                 float* __restrict__ h, int norm) {
    int wid  = (blockIdx.x * blockDim.x + threadIdx.x) >> 6;
    int lane = threadIdx.x & 63;
    int sl   = lane & 31;
    int node = wid * 2 + (lane >> 5);
    if (node >= N_NODES) return;
    int beg = ptr[node], end = ptr[node + 1];
    int deg = end - beg;
    const float* zrow = z + sl * 4;
    float ax = 0.f, ay = 0.f, az = 0.f, aw = 0.f;
    for (int base = 0; base < deg; base += 32) {
        int m = deg - base;
        if (m > 32) m = 32;
        int idx = (sl < m) ? adj[beg + base + sl] : 0;
        int j = 0;
        for (; j + 8 <= m; j += 8) {
            int n0 = __shfl(idx, j,     32);
            int n1 = __shfl(idx, j + 1, 32);
            int n2 = __shfl(idx, j + 2, 32);
            int n3 = __shfl(idx, j + 3, 32);
            int n4 = __shfl(idx, j + 4, 32);
            int n5 = __shfl(idx, j + 5, 32);
            int n6 = __shfl(idx, j + 6, 32);
            int n7 = __shfl(idx, j + 7, 32);
            float4 v0 = *(const float4*)(zrow + (size_t)n0 * H);
            float4 v1 = *(const float4*)(zrow + (size_t)n1 * H);
            float4 v2 = *(const float4*)(zrow + (size_t)n2 * H);
            float4 v3 = *(const float4*)(zrow + (size_t)n3 * H);
            float4 v4 = *(const float4*)(zrow + (size_t)n4 * H);
            float4 v5 = *(const float4*)(zrow + (size_t)n5 * H);
            float4 v6 = *(const float4*)(zrow + (size_t)n6 * H);
            float4 v7 = *(const float4*)(zrow + (size_t)n7 * H);
            ax += ((v0.x + v1.x) + (v2.x + v3.x)) + ((v4.x + v5.x) + (v6.x + v7.x));
            ay += ((v0.y + v1.y) + (v2.y + v3.y)) + ((v4.y + v5.y) + (v6.y + v7.y));
            az += ((v0.z + v1.z) + (v2.z + v3.z)) + ((v4.z + v5.z) + (v6.z + v7.z));
            aw += ((v0.w + v1.w) + (v2.w + v3.w)) + ((v4.w + v5.w) + (v6.w + v7.w));
        }
        for (; j + 4 <= m; j += 4) {
            int n0 = __shfl(idx, j,     32);
            int n1 = __shfl(idx, j + 1, 32);
            int n2 = __shfl(idx, j + 2, 32);
            int n3 = __shfl(idx, j + 3, 32);
            float4 v0 = *(const float4*)(zrow + (size_t)n0 * H);
            float4 v1 = *(const float4*)(zrow + (size_t)n1 * H);
            float4 v2 = *(const float4*)(zrow + (size_t)n2 * H);
            float4 v3 = *(const float4*)(zrow + (size_t)n3 * H);
            ax += (v0.x + v1.x) + (v2.x + v3.x);
            ay += (v0.y + v1.y) + (v2.y + v3.y);
            az += (v0.z + v1.z) + (v2.z + v3.z);
            aw += (v0.w + v1.w) + (v2.w + v3.w);
        }
        for (; j < m; ++j) {
            int n0 = __shfl(idx, j, 32);
            float4 v0 = *(const float4*)(zrow + (size_t)n0 * H);
            ax += v0.x; ay += v0.y; az += v0.z; aw += v0.w;
        }
    }
    float inv = 1.0f / (float)(deg > 1 ? deg : 1);
    float4 yv = *(const float4*)(y + (size_t)node * H + sl * 4);
    float4 bv = *(const float4*)(bl + sl * 4);
    float vx = ax * inv + bv.x + yv.x;
    float vy = ay * inv + bv.y + yv.y;
    float vz = az * inv + bv.z + yv.z;
    float vw = aw * inv + bv.w + yv.w;
    if (norm) {
        float ss = vx * vx + vy * vy + vz * vz + vw * vw;
#pragma unroll
        for (int m = 1; m < 32; m <<= 1) ss += __shfl_xor(ss, m, 32);
        float n2 = 1.0f / fmaxf(sqrtf(ss), 1e-12f);
        vx *= n2; vy *= n2; vz *= n2; vw *= n2;
    }
    *(float4*)(h + (size_t)node * H + sl * 4) = make_float4(vx, vy, vz, vw);
}

// ---------------- global add pool (batch sorted) ----------------

constexpr int POOL_ROWS = 64;

__global__ void k_pool(const float* __restrict__ h, const int* __restrict__ batch,
                       float* __restrict__ g) {
    int col = threadIdx.x;  // 0..127
    int r0 = blockIdx.x * POOL_ROWS;
    int r1 = r0 + POOL_ROWS;
    if (r1 > N_NODES) r1 = N_NODES;
    if (r0 >= N_NODES) return;
    float acc = 0.f;
    int cur = batch[r0];
    int r = r0;
    for (; r + 4 <= r1; r += 4) {
        float v0 = h[(size_t)r * H + col];
        float v1 = h[(size_t)(r + 1) * H + col];
        float v2 = h[(size_t)(r + 2) * H + col];
        float v3 = h[(size_t)(r + 3) * H + col];
        int b3 = batch[r + 3];
        if (b3 == cur) {
            acc += (v0 + v1) + (v2 + v3);
        } else {
            int b0 = batch[r], b1 = batch[r + 1], b2 = batch[r + 2];
            if (b0 != cur) { atomicAdd(&g[cur * H + col], acc); acc = 0.f; cur = b0; }
            acc += v0;
            if (b1 != cur) { atomicAdd(&g[cur * H + col], acc); acc = 0.f; cur = b1; }
            acc += v1;
            if (b2 != cur) { atomicAdd(&g[cur * H + col], acc); acc = 0.f; cur = b2; }
            acc += v2;
            if (b3 != cur) { atomicAdd(&g[cur * H + col], acc); acc = 0.f; cur = b3; }
            acc += v3;
        }
    }
    for (; r < r1; ++r) {
        int b = batch[r];
        if (b != cur) { atomicAdd(&g[cur * H + col], acc); acc = 0.f; cur = b; }
        acc += h[(size_t)r * H + col];
    }
    atomicAdd(&g[cur * H + col], acc);
}

// ---------------- MLP head ----------------

__global__ void k_mlp(const float* __restrict__ g, const float* __restrict__ W0,
                      const float* __restrict__ b0, const float* __restrict__ W1,
                      const float* __restrict__ b1, const float* __restrict__ Wh,
                      const float* __restrict__ bh, float* __restrict__ out) {
    int gi = blockIdx.x;
    int t  = threadIdx.x;  // 0..127
    __shared__ float buf0[H];
    __shared__ float buf1[H];
    __shared__ float red[2];

    float acc = b0[t];
    for (int k = 0; k < H; ++k) acc += g[gi * H + k] * W0[k * H + t];
    buf0[t] = fmaxf(acc, 0.f);
    __syncthreads();

    acc = b1[t];
    for (int k = 0; k < H; ++k) acc += buf0[k] * W1[k * H + t];
    buf1[t] = fmaxf(acc, 0.f);
    __syncthreads();

    float p = buf1[t] * Wh[t];
    for (int m = 1; m < 64; m <<= 1) p += __shfl_xor(p, m, 64);
    if ((t & 63) == 0) red[t >> 6] = p;
    __syncthreads();
    if (t == 0) out[gi] = red[0] + red[1] + bh[0];
}

// ---------------- driver ----------------

extern "C" void kernel_launch(void* const* d_in, const int* in_sizes, int n_in,
                              void* d_out, int out_size, void* d_ws, size_t ws_size,
                              hipStream_t stream) {
    const float* x     = (const float*)d_in[0];
    const int*   eic   = (const int*)d_in[1];
    const int*   eid   = (const int*)d_in[2];
    const int*   eit   = (const int*)d_in[3];
    const int*   batch = (const int*)d_in[4];
    const float* cW[5][3];
    for (int c = 0; c < 5; ++c) {
        cW[c][0] = (const float*)d_in[5 + c * 3 + 0];  // Wl
        cW[c][1] = (const float*)d_in[5 + c * 3 + 1];  // bl
        cW[c][2] = (const float*)d_in[5 + c * 3 + 2];  // Wr
    }
    const float* l0_W = (const float*)d_in[20];
    const float* l0_b = (const float*)d_in[21];
    const float* l1_W = (const float*)d_in[22];
    const float* l1_b = (const float*)d_in[23];
    const float* hd_W = (const float*)d_in[24];
    const float* hd_b = (const float*)d_in[25];
    float* outp = (float*)d_out;

    const size_t NH = (size_t)N_NODES * H;
    float* hbuf = (float*)d_ws;
    float* zbuf = hbuf + NH;
    float* ybuf = zbuf + NH;
    float* gbuf = ybuf + NH;
    int* iws  = (int*)(gbuf + (size_t)NG * H);
    int* ptr0 = iws;
    int* ptr1 = ptr0 + (N_NODES + 1);
    int* ptr2 = ptr1 + (N_NODES + 1);
    int* adj0 = ptr2 + (N_NODES + 1);
    int* adj1 = adj0 + NE;
    int* adj2 = adj1 + NE;
    int* fill = adj2 + NE;
    int* bsum = fill + N_NODES;

    const int* esrc[3] = {eic, eid, eit};
    int* ptrs[3] = {ptr0, ptr1, ptr2};
    int* adjs[3] = {adj0, adj1, adj2};

    dim3 b256(256);
    dim3 gE((NE + 255) / 256);

    for (int s = 0; s < 3; ++s) {
        hipMemsetAsync(fill, 0, N_NODES * sizeof(int), stream);
        k_count<<<gE, b256, 0, stream>>>(esrc[s] + NE, fill);
        k_bsum<<<dim3(SCAN_G), b256, 0, stream>>>(fill, bsum);
        k_bscan<<<dim3(1), b256, 0, stream>>>(bsum, ptrs[s]);
        k_bwrite<<<dim3(SCAN_G), b256, 0, stream>>>(fill, bsum, ptrs[s], fill);
        k_build<<<gE, b256, 0, stream>>>(esrc[s], esrc[s] + NE, fill, adjs[s]);
    }

    const int L_set[7]  = {1, 0, 0, 2, 1, 0, 0};
    const int L_conv[7] = {0, 1, 1, 2, 3, 4, 4};
    const int L_norm[7] = {1, 1, 1, 0, 1, 1, 1};

    int nWaves = (N_NODES + 1) / 2;      // 2 nodes per wave
    dim3 gAgg((nWaves + 3) / 4);         // 4 waves/block
    dim3 gGemm((N_NODES + BM - 1) / BM); // 782 blocks of 256 thr

    const float* hin = x;
    for (int L = 0; L < 7; ++L) {
        int s = L_set[L], c = L_conv[L];
        k_gemm<<<gGemm, b256, 0, stream>>>(hin, cW[c][0], cW[c][2], zbuf, ybuf);
        k_aggnorm<<<gAgg, b256, 0, stream>>>(zbuf, ybuf, ptrs[s], adjs[s], cW[c][1],
                                             hbuf, L_norm[L]);
        hin = hbuf;  // in-place across layers: aggnorm reads only z,y
    }

    hipMemsetAsync(gbuf, 0, (size_t)NG * H * sizeof(float), stream);
    k_pool<<<dim3((N_NODES + POOL_ROWS - 1) / POOL_ROWS), dim3(H), 0, stream>>>(
        hin, batch, gbuf);
    k_mlp<<<dim3(NG), dim3(H), 0, stream>>>(gbuf, l0_W, l0_b, l1_W, l1_b, hd_W, hd_b,
                                            outp);
}

// Round 6
// 714.983 us; speedup vs baseline: 1.5765x; 1.4983x over previous
//
#include <hip/hip_runtime.h>
#include <hip/hip_bf16.h>

// ValueNet: 7x SAGEConv(mean) + global_add_pool + MLP head.
// N=50000 nodes, E=600000 edges/set, H=128, G=64 graphs.
//
// Layer reformulation (linearity of mean):
//   out_i = mean_j(z_j) + bl + y_i,  z = h@Wl, y = h@Wr.
// GEMM runs on MFMA bf16 with SPLIT PRECISION (h = hi + lo, W = hi + lo;
// D = Ahi*Bhi + Ahi*Blo + Alo*Bhi, fp32 accumulate -> ~fp32 fidelity).
// z,y stored bf16 (storage rounding ~1e-3 rel only); h stored as hi/lo planes.

constexpr int N_NODES = 50000;
constexpr int NE      = 600000;
constexpr int H       = 128;
constexpr int NG      = 64;

typedef __attribute__((ext_vector_type(8))) short short8;
typedef __attribute__((ext_vector_type(4))) float f32x4;

__device__ __forceinline__ ushort f2bf(float f) {  // RNE float->bf16
    uint x = __float_as_uint(f);
    return (ushort)((x + 0x7FFFu + ((x >> 16) & 1u)) >> 16);
}
__device__ __forceinline__ float bf2f(ushort u) {
    return __uint_as_float(((uint)u) << 16);
}

// ---------------- CSR build (counting sort by dst) ----------------

__global__ void k_count(const int* __restrict__ dst, int* __restrict__ cnt) {
    int e = blockIdx.x * blockDim.x + threadIdx.x;
    if (e < NE) atomicAdd(&cnt[dst[e]], 1);
}

constexpr int SCAN_B = 256;
constexpr int SCAN_G = (N_NODES + SCAN_B - 1) / SCAN_B;  // 196

__global__ void k_bsum(const int* __restrict__ cnt, int* __restrict__ bsum) {
    __shared__ int sh[SCAN_B];
    int t = threadIdx.x;
    int i = blockIdx.x * SCAN_B + t;
    sh[t] = (i < N_NODES) ? cnt[i] : 0;
    __syncthreads();
    for (int off = SCAN_B / 2; off > 0; off >>= 1) {
        if (t < off) sh[t] += sh[t + off];
        __syncthreads();
    }
    if (t == 0) bsum[blockIdx.x] = sh[0];
}

__global__ void k_bscan(int* bsum, int* ptr) {
    __shared__ int sh[SCAN_B];
    int t = threadIdx.x;
    int v = (t < SCAN_G) ? bsum[t] : 0;
    sh[t] = v;
    __syncthreads();
    for (int off = 1; off < SCAN_B; off <<= 1) {
        int u = (t >= off) ? sh[t - off] : 0;
        __syncthreads();
        if (t >= off) sh[t] += u;
        __syncthreads();
    }
    if (t < SCAN_G) bsum[t] = sh[t] - v;
    if (t == 0) ptr[N_NODES] = sh[SCAN_B - 1];
}

__global__ void k_bwrite(const int* cnt, const int* __restrict__ boff,
                         int* __restrict__ ptr, int* fill) {
    __shared__ int sh[SCAN_B];
    int t = threadIdx.x;
    int i = blockIdx.x * SCAN_B + t;
    int v = (i < N_NODES) ? cnt[i] : 0;
    sh[t] = v;
    __syncthreads();
    for (int off = 1; off < SCAN_B; off <<= 1) {
        int u = (t >= off) ? sh[t - off] : 0;
        __syncthreads();
        if (t >= off) sh[t] += u;
        __syncthreads();
    }
    int excl = sh[t] - v + boff[blockIdx.x];
    if (i < N_NODES) {
        ptr[i]  = excl;
        fill[i] = excl;
    }
}

__global__ void k_build(const int* __restrict__ src, const int* __restrict__ dst,
                        int* __restrict__ fill, int* __restrict__ adj) {
    int e = blockIdx.x * blockDim.x + threadIdx.x;
    if (e < NE) {
        int pos = atomicAdd(&fill[dst[e]], 1);
        adj[pos] = src[e];
    }
}

// ---------------- split x (fp32) -> hi/lo bf16 planes ----------------

__global__ void k_split(const float* __restrict__ x, ushort* __restrict__ hi,
                        ushort* __restrict__ lo) {
    size_t i = ((size_t)blockIdx.x * 256 + threadIdx.x) * 4;
    if (i >= (size_t)N_NODES * H) return;
    float4 v = *(const float4*)(x + i);
    ushort4 h, l;
    h.x = f2bf(v.x); l.x = f2bf(v.x - bf2f(h.x));
    h.y = f2bf(v.y); l.y = f2bf(v.y - bf2f(h.y));
    h.z = f2bf(v.z); l.z = f2bf(v.z - bf2f(h.z));
    h.w = f2bf(v.w); l.w = f2bf(v.w - bf2f(h.w));
    *(ushort4*)(hi + i) = h;
    *(ushort4*)(lo + i) = l;
}

// ---------------- weight pre-scatter into MFMA fragment order ----------------
// B = [Wl | Wr]  (128 k x 256 n). Element (k,n), k = q*32 + g*8 + j, stored at
// ((q*4+g)*256 + n)*8 + j  -> per-lane frag loads are contiguous 16B.

__global__ void k_wsplit(const float* __restrict__ Wl, const float* __restrict__ Wr,
                         ushort* __restrict__ bh, ushort* __restrict__ blo) {
    int idx = blockIdx.x * 256 + threadIdx.x;  // 0..32767
    if (idx >= 128 * 256) return;
    int n = idx & 255, k = idx >> 8;
    float w = (n < H) ? Wl[k * H + n] : Wr[k * H + (n - H)];
    int q = k >> 5, g = (k >> 3) & 3, j = k & 7;
    int off = ((q * 4 + g) * 256 + n) * 8 + j;
    ushort h = f2bf(w);
    bh[off]  = h;
    blo[off] = f2bf(w - bf2f(h));
}

// ---------------- MFMA GEMM: (z,y) = (Ahi+Alo) @ (Bhi+Blo) ----------------
// Block 256 thr = 4 waves. Tile 64 rows x 256 cols; wave w -> 64-col strip.
// A staged in LDS (both planes, padded rows: stride 136 -> conflict-free).
// B frags loaded per-lane contiguous from pre-scattered global (L2-resident).
// 3 MFMAs per (tile, k-chunk): hi*hi + hi*lo + lo*hi.

__global__ __launch_bounds__(256) void k_gemm_mfma(
    const ushort* __restrict__ Ahi, const ushort* __restrict__ Alo,
    const ushort* __restrict__ Bh, const ushort* __restrict__ Bl,
    ushort* __restrict__ z, ushort* __restrict__ yb) {
    __shared__ ushort Ash[2][64][136];
    int t = threadIdx.x;
    int rowBase = blockIdx.x * 64;
    {
        int plane = t >> 7;         // 0,1
        int row   = (t >> 1) & 63;
        int half  = t & 1;          // 64-elem halves
        const ushort* Ap = plane ? Alo : Ahi;
        int grow = rowBase + row;
        if (grow > N_NODES - 1) grow = N_NODES - 1;
        const int4* src = (const int4*)(Ap + (size_t)grow * H + half * 64);
        int4* dst = (int4*)&Ash[plane][row][half * 64];
#pragma unroll
        for (int i = 0; i < 8; ++i) dst[i] = src[i];
    }
    __syncthreads();

    int wave = t >> 6, lane = t & 63;
    int m16 = lane & 15, q4 = lane >> 4;
    int n0 = wave * 64;

    f32x4 acc[4][4];
#pragma unroll
    for (int r = 0; r < 4; ++r)
#pragma unroll
        for (int c = 0; c < 4; ++c) {
            acc[r][c][0] = 0.f; acc[r][c][1] = 0.f;
            acc[r][c][2] = 0.f; acc[r][c][3] = 0.f;
        }

    for (int q = 0; q < 4; ++q) {
        short8 bh_[4], bl_[4], ah_[4], al_[4];
#pragma unroll
        for (int c = 0; c < 4; ++c) {
            int boff = ((q * 4 + q4) * 256 + n0 + c * 16 + m16) * 8;
            bh_[c] = *(const short8*)(Bh + boff);
            bl_[c] = *(const short8*)(Bl + boff);
        }
#pragma unroll
        for (int r = 0; r < 4; ++r) {
            ah_[r] = *(const short8*)&Ash[0][r * 16 + m16][q * 32 + q4 * 8];
            al_[r] = *(const short8*)&Ash[1][r * 16 + m16][q * 32 + q4 * 8];
        }
#pragma unroll
        for (int r = 0; r < 4; ++r)
#pragma unroll
            for (int c = 0; c < 4; ++c) {
                acc[r][c] = __builtin_amdgcn_mfma_f32_16x16x32_bf16(
                    ah_[r], bh_[c], acc[r][c], 0, 0, 0);
                acc[r][c] = __builtin_amdgcn_mfma_f32_16x16x32_bf16(
                    ah_[r], bl_[c], acc[r][c], 0, 0, 0);
                acc[r][c] = __builtin_amdgcn_mfma_f32_16x16x32_bf16(
                    al_[r], bh_[c], acc[r][c], 0, 0, 0);
            }
    }

    // epilogue: C/D layout col=lane&15, row=(lane>>4)*4+reg (m89-verified)
#pragma unroll
    for (int r = 0; r < 4; ++r)
#pragma unroll
        for (int c = 0; c < 4; ++c) {
            int col = n0 + c * 16 + m16;
            ushort* op = (col < H) ? (z + col) : (yb + (col - H));
#pragma unroll
            for (int j = 0; j < 4; ++j) {
                int gr = rowBase + r * 16 + q4 * 4 + j;
                if (gr < N_NODES) op[(size_t)gr * H] = f2bf(acc[r][c][j]);
            }
        }
}

// ---------------- gather + epilogue: h = split(norm(mean_j z_j + bl + y)) ----------------
// One 32-lane half-wave per node; z rows are 256B (bf16), 8B/lane.

__global__ __launch_bounds__(256) void k_aggnorm(
    const ushort* __restrict__ z, const ushort* __restrict__ yb,
    const int* __restrict__ ptr, const int* __restrict__ adj,
    const float* __restrict__ bl,
    ushort* __restrict__ hhi, ushort* __restrict__ hlo, int norm) {
    int wid  = (blockIdx.x * blockDim.x + threadIdx.x) >> 6;
    int lane = threadIdx.x & 63;
    int sl   = lane & 31;
    int node = wid * 2 + (lane >> 5);
    if (node >= N_NODES) return;
    int beg = ptr[node], end = ptr[node + 1];
    int deg = end - beg;
    const ushort* zrow = z + sl * 4;
    float a0 = 0.f, a1 = 0.f, a2 = 0.f, a3 = 0.f;
    for (int base = 0; base < deg; base += 32) {
        int m = deg - base;
        if (m > 32) m = 32;
        int idx = (sl < m) ? adj[beg + base + sl] : 0;
        int j = 0;
        for (; j + 8 <= m; j += 8) {
            int n0 = __shfl(idx, j,     32);
            int n1 = __shfl(idx, j + 1, 32);
            int n2 = __shfl(idx, j + 2, 32);
            int n3 = __shfl(idx, j + 3, 32);
            int n4 = __shfl(idx, j + 4, 32);
            int n5 = __shfl(idx, j + 5, 32);
            int n6 = __shfl(idx, j + 6, 32);
            int n7 = __shfl(idx, j + 7, 32);
            ushort4 v0 = *(const ushort4*)(zrow + (size_t)n0 * H);
            ushort4 v1 = *(const ushort4*)(zrow + (size_t)n1 * H);
            ushort4 v2 = *(const ushort4*)(zrow + (size_t)n2 * H);
            ushort4 v3 = *(const ushort4*)(zrow + (size_t)n3 * H);
            ushort4 v4 = *(const ushort4*)(zrow + (size_t)n4 * H);
            ushort4 v5 = *(const ushort4*)(zrow + (size_t)n5 * H);
            ushort4 v6 = *(const ushort4*)(zrow + (size_t)n6 * H);
            ushort4 v7 = *(const ushort4*)(zrow + (size_t)n7 * H);
            a0 += ((bf2f(v0.x) + bf2f(v1.x)) + (bf2f(v2.x) + bf2f(v3.x))) +
                  ((bf2f(v4.x) + bf2f(v5.x)) + (bf2f(v6.x) + bf2f(v7.x)));
            a1 += ((bf2f(v0.y) + bf2f(v1.y)) + (bf2f(v2.y) + bf2f(v3.y))) +
                  ((bf2f(v4.y) + bf2f(v5.y)) + (bf2f(v6.y) + bf2f(v7.y)));
            a2 += ((bf2f(v0.z) + bf2f(v1.z)) + (bf2f(v2.z) + bf2f(v3.z))) +
                  ((bf2f(v4.z) + bf2f(v5.z)) + (bf2f(v6.z) + bf2f(v7.z)));
            a3 += ((bf2f(v0.w) + bf2f(v1.w)) + (bf2f(v2.w) + bf2f(v3.w))) +
                  ((bf2f(v4.w) + bf2f(v5.w)) + (bf2f(v6.w) + bf2f(v7.w)));
        }
        for (; j + 4 <= m; j += 4) {
            int n0 = __shfl(idx, j,     32);
            int n1 = __shfl(idx, j + 1, 32);
            int n2 = __shfl(idx, j + 2, 32);
            int n3 = __shfl(idx, j + 3, 32);
            ushort4 v0 = *(const ushort4*)(zrow + (size_t)n0 * H);
            ushort4 v1 = *(const ushort4*)(zrow + (size_t)n1 * H);
            ushort4 v2 = *(const ushort4*)(zrow + (size_t)n2 * H);
            ushort4 v3 = *(const ushort4*)(zrow + (size_t)n3 * H);
            a0 += (bf2f(v0.x) + bf2f(v1.x)) + (bf2f(v2.x) + bf2f(v3.x));
            a1 += (bf2f(v0.y) + bf2f(v1.y)) + (bf2f(v2.y) + bf2f(v3.y));
            a2 += (bf2f(v0.z) + bf2f(v1.z)) + (bf2f(v2.z) + bf2f(v3.z));
            a3 += (bf2f(v0.w) + bf2f(v1.w)) + (bf2f(v2.w) + bf2f(v3.w));
        }
        for (; j < m; ++j) {
            int n0 = __shfl(idx, j, 32);
            ushort4 v0 = *(const ushort4*)(zrow + (size_t)n0 * H);
            a0 += bf2f(v0.x); a1 += bf2f(v0.y); a2 += bf2f(v0.z); a3 += bf2f(v0.w);
        }
    }
    float inv = 1.0f / (float)(deg > 1 ? deg : 1);
    ushort4 yv = *(const ushort4*)(yb + (size_t)node * H + sl * 4);
    float4 bv = *(const float4*)(bl + sl * 4);
    float v0 = a0 * inv + bv.x + bf2f(yv.x);
    float v1 = a1 * inv + bv.y + bf2f(yv.y);
    float v2 = a2 * inv + bv.z + bf2f(yv.z);
    float v3 = a3 * inv + bv.w + bf2f(yv.w);
    if (norm) {
        float ss = v0 * v0 + v1 * v1 + v2 * v2 + v3 * v3;
#pragma unroll
        for (int m = 1; m < 32; m <<= 1) ss += __shfl_xor(ss, m, 32);
        float n2 = 1.0f / fmaxf(sqrtf(ss), 1e-12f);
        v0 *= n2; v1 *= n2; v2 *= n2; v3 *= n2;
    }
    ushort4 h, l;
    h.x = f2bf(v0); l.x = f2bf(v0 - bf2f(h.x));
    h.y = f2bf(v1); l.y = f2bf(v1 - bf2f(h.y));
    h.z = f2bf(v2); l.z = f2bf(v2 - bf2f(h.z));
    h.w = f2bf(v3); l.w = f2bf(v3 - bf2f(h.w));
    *(ushort4*)(hhi + (size_t)node * H + sl * 4) = h;
    *(ushort4*)(hlo + (size_t)node * H + sl * 4) = l;
}

// ---------------- global add pool (batch sorted), h = hi + lo ----------------

constexpr int POOL_ROWS = 64;

__global__ void k_pool(const ushort* __restrict__ hhi, const ushort* __restrict__ hlo,
                       const int* __restrict__ batch, float* __restrict__ g) {
    int col = threadIdx.x;  // 0..127
    int r0 = blockIdx.x * POOL_ROWS;
    int r1 = r0 + POOL_ROWS;
    if (r1 > N_NODES) r1 = N_NODES;
    if (r0 >= N_NODES) return;
    float acc = 0.f;
    int cur = batch[r0];
    int r = r0;
    for (; r + 4 <= r1; r += 4) {
        float v0 = bf2f(hhi[(size_t)r * H + col])       + bf2f(hlo[(size_t)r * H + col]);
        float v1 = bf2f(hhi[(size_t)(r + 1) * H + col]) + bf2f(hlo[(size_t)(r + 1) * H + col]);
        float v2 = bf2f(hhi[(size_t)(r + 2) * H + col]) + bf2f(hlo[(size_t)(r + 2) * H + col]);
        float v3 = bf2f(hhi[(size_t)(r + 3) * H + col]) + bf2f(hlo[(size_t)(r + 3) * H + col]);
        int b3 = batch[r + 3];
        if (b3 == cur) {
            acc += (v0 + v1) + (v2 + v3);
        } else {
            int b0 = batch[r], b1 = batch[r + 1], b2 = batch[r + 2];
            if (b0 != cur) { atomicAdd(&g[cur * H + col], acc); acc = 0.f; cur = b0; }
            acc += v0;
            if (b1 != cur) { atomicAdd(&g[cur * H + col], acc); acc = 0.f; cur = b1; }
            acc += v1;
            if (b2 != cur) { atomicAdd(&g[cur * H + col], acc); acc = 0.f; cur = b2; }
            acc += v2;
            if (b3 != cur) { atomicAdd(&g[cur * H + col], acc); acc = 0.f; cur = b3; }
            acc += v3;
        }
    }
    for (; r < r1; ++r) {
        int b = batch[r];
        if (b != cur) { atomicAdd(&g[cur * H + col], acc); acc = 0.f; cur = b; }
        acc += bf2f(hhi[(size_t)r * H + col]) + bf2f(hlo[(size_t)r * H + col]);
    }
    atomicAdd(&g[cur * H + col], acc);
}

// ---------------- MLP head ----------------

__global__ void k_mlp(const float* __restrict__ g, const float* __restrict__ W0,
                      const float* __restrict__ b0, const float* __restrict__ W1,
                      const float* __restrict__ b1, const float* __restrict__ Wh,
                      const float* __restrict__ bh, float* __restrict__ out) {
    int gi = blockIdx.x;
    int t  = threadIdx.x;  // 0..127
    __shared__ float buf0[H];
    __shared__ float buf1[H];
    __shared__ float red[2];

    float acc = b0[t];
    for (int k = 0; k < H; ++k) acc += g[gi * H + k] * W0[k * H + t];
    buf0[t] = fmaxf(acc, 0.f);
    __syncthreads();

    acc = b1[t];
    for (int k = 0; k < H; ++k) acc += buf0[k] * W1[k * H + t];
    buf1[t] = fmaxf(acc, 0.f);
    __syncthreads();

    float p = buf1[t] * Wh[t];
    for (int m = 1; m < 64; m <<= 1) p += __shfl_xor(p, m, 64);
    if ((t & 63) == 0) red[t >> 6] = p;
    __syncthreads();
    if (t == 0) out[gi] = red[0] + red[1] + bh[0];
}

// ---------------- driver ----------------

extern "C" void kernel_launch(void* const* d_in, const int* in_sizes, int n_in,
                              void* d_out, int out_size, void* d_ws, size_t ws_size,
                              hipStream_t stream) {
    const float* x     = (const float*)d_in[0];
    const int*   eic   = (const int*)d_in[1];
    const int*   eid   = (const int*)d_in[2];
    const int*   eit   = (const int*)d_in[3];
    const int*   batch = (const int*)d_in[4];
    const float* cW[5][3];
    for (int c = 0; c < 5; ++c) {
        cW[c][0] = (const float*)d_in[5 + c * 3 + 0];  // Wl
        cW[c][1] = (const float*)d_in[5 + c * 3 + 1];  // bl
        cW[c][2] = (const float*)d_in[5 + c * 3 + 2];  // Wr
    }
    const float* l0_W = (const float*)d_in[20];
    const float* l0_b = (const float*)d_in[21];
    const float* l1_W = (const float*)d_in[22];
    const float* l1_b = (const float*)d_in[23];
    const float* hd_W = (const float*)d_in[24];
    const float* hd_b = (const float*)d_in[25];
    float* outp = (float*)d_out;

    const size_t NH = (size_t)N_NODES * H;
    ushort* Ahi = (ushort*)d_ws;
    ushort* Alo = Ahi + NH;
    ushort* zb  = Alo + NH;
    ushort* yb  = zb + NH;
    ushort* Bpk = yb + NH;                     // 5 convs x 2 planes x 32768
    float*  gbuf = (float*)(Bpk + 5 * 2 * 32768);
    int* iws  = (int*)(gbuf + (size_t)NG * H);
    int* ptr0 = iws;
    int* ptr1 = ptr0 + (N_NODES + 1);
    int* ptr2 = ptr1 + (N_NODES + 1);
    int* adj0 = ptr2 + (N_NODES + 1);
    int* adj1 = adj0 + NE;
    int* adj2 = adj1 + NE;
    int* fill = adj2 + NE;
    int* bsum = fill + N_NODES;

    const int* esrc[3] = {eic, eid, eit};
    int* ptrs[3] = {ptr0, ptr1, ptr2};
    int* adjs[3] = {adj0, adj1, adj2};

    dim3 b256(256);
    dim3 gE((NE + 255) / 256);

    // weight pre-scatter (5 convs)
    for (int c = 0; c < 5; ++c) {
        k_wsplit<<<dim3(128), b256, 0, stream>>>(cW[c][0], cW[c][2],
                                                 Bpk + (size_t)c * 65536,
                                                 Bpk + (size_t)c * 65536 + 32768);
    }
    // split x into hi/lo planes
    k_split<<<dim3((int)(NH / 1024)), b256, 0, stream>>>(x, Ahi, Alo);

    // build 3 CSRs (dst-sorted)
    for (int s = 0; s < 3; ++s) {
        hipMemsetAsync(fill, 0, N_NODES * sizeof(int), stream);
        k_count<<<gE, b256, 0, stream>>>(esrc[s] + NE, fill);
        k_bsum<<<dim3(SCAN_G), b256, 0, stream>>>(fill, bsum);
        k_bscan<<<dim3(1), b256, 0, stream>>>(bsum, ptrs[s]);
        k_bwrite<<<dim3(SCAN_G), b256, 0, stream>>>(fill, bsum, ptrs[s], fill);
        k_build<<<gE, b256, 0, stream>>>(esrc[s], esrc[s] + NE, fill, adjs[s]);
    }

    const int L_set[7]  = {1, 0, 0, 2, 1, 0, 0};
    const int L_conv[7] = {0, 1, 1, 2, 3, 4, 4};
    const int L_norm[7] = {1, 1, 1, 0, 1, 1, 1};

    int nWaves = (N_NODES + 1) / 2;
    dim3 gAgg((nWaves + 3) / 4);
    dim3 gGemm((N_NODES + 63) / 64);   // 782

    for (int L = 0; L < 7; ++L) {
        int s = L_set[L], c = L_conv[L];
        const ushort* Bh = Bpk + (size_t)c * 65536;
        const ushort* Bl = Bh + 32768;
        k_gemm_mfma<<<gGemm, b256, 0, stream>>>(Ahi, Alo, Bh, Bl, zb, yb);
        k_aggnorm<<<gAgg, b256, 0, stream>>>(zb, yb, ptrs[s], adjs[s], cW[c][1],
                                             Ahi, Alo, L_norm[L]);
    }

    hipMemsetAsync(gbuf, 0, (size_t)NG * H * sizeof(float), stream);
    k_pool<<<dim3((N_NODES + POOL_ROWS - 1) / POOL_ROWS), dim3(H), 0, stream>>>(
        Ahi, Alo, batch, gbuf);
    k_mlp<<<dim3(NG), dim3(H), 0, stream>>>(gbuf, l0_W, l0_b, l1_W, l1_b, hd_W, hd_b,
                                            outp);
}

// Round 9
// 707.113 us; speedup vs baseline: 1.5941x; 1.0111x over previous
//
#include <hip/hip_runtime.h>
#include <hip/hip_bf16.h>

// ValueNet: 7x SAGEConv(mean) + global_add_pool + MLP head.
// N=50000 nodes, E=600000 edges/set, H=128, G=64 graphs.
//
// out_i = mean_j(z_j) + bl + y_i,  z = h@Wl, y = h@Wr (linearity of mean).
// GEMM on MFMA bf16 with split precision (hi+lo planes, 3 MFMAs: hh+hl+lh).
// z,y stored bf16. h stored as hi/lo bf16 planes.
//
// R9 bisection: combined CSR build (toy-verified) + R6's PROVEN k_aggnorm.
// CSR scratch (fill/bsum) aliases zb (dead until first gemm, stream-ordered).

constexpr int N_NODES = 50000;
constexpr int NE      = 600000;
constexpr int H       = 128;
constexpr int NG      = 64;
constexpr int N3      = 3 * N_NODES;   // 150000

typedef __attribute__((ext_vector_type(8))) short short8;
typedef __attribute__((ext_vector_type(4))) float f32x4;

__device__ __forceinline__ ushort f2bf(float f) {  // RNE float->bf16
    uint x = __float_as_uint(f);
    return (ushort)((x + 0x7FFFu + ((x >> 16) & 1u)) >> 16);
}
__device__ __forceinline__ float bf2f(ushort u) {
    return __uint_as_float(((uint)u) << 16);
}

// ---------------- CSR build: all 3 edge sets in one pass ----------------

__global__ void k_count3(const int* __restrict__ e0, const int* __restrict__ e1,
                         const int* __restrict__ e2, int* __restrict__ cnt) {
    int e = blockIdx.x * blockDim.x + threadIdx.x;
    if (e >= 3 * NE) return;
    int s = e / NE, r = e - s * NE;
    const int* dst = (s == 0 ? e0 : (s == 1 ? e1 : e2)) + NE;
    atomicAdd(&cnt[s * N_NODES + dst[r]], 1);
}

constexpr int SCAN_B  = 256;
constexpr int SCAN_G3 = (N3 + SCAN_B - 1) / SCAN_B;  // 586

__global__ void k_bsum(const int* __restrict__ cnt, int* __restrict__ bsum) {
    __shared__ int sh[SCAN_B];
    int t = threadIdx.x;
    int i = blockIdx.x * SCAN_B + t;
    sh[t] = (i < N3) ? cnt[i] : 0;
    __syncthreads();
    for (int off = SCAN_B / 2; off > 0; off >>= 1) {
        if (t < off) sh[t] += sh[t + off];
        __syncthreads();
    }
    if (t == 0) bsum[blockIdx.x] = sh[0];
}

__global__ void k_bscan(int* bsum, int* ptr) {  // 1 block, 1024 threads
    __shared__ int sh[1024];
    int t = threadIdx.x;
    int v = (t < SCAN_G3) ? bsum[t] : 0;
    sh[t] = v;
    __syncthreads();
    for (int off = 1; off < 1024; off <<= 1) {
        int u = (t >= off) ? sh[t - off] : 0;
        __syncthreads();
        if (t >= off) sh[t] += u;
        __syncthreads();
    }
    if (t < SCAN_G3) bsum[t] = sh[t] - v;     // exclusive block offsets
    if (t == 0) ptr[N3] = sh[1023];           // total = 3*NE
}

__global__ void k_bwrite(const int* cnt, const int* __restrict__ boff,
                         int* __restrict__ ptr, int* fill) {
    __shared__ int sh[SCAN_B];
    int t = threadIdx.x;
    int i = blockIdx.x * SCAN_B + t;
    int v = (i < N3) ? cnt[i] : 0;
    sh[t] = v;
    __syncthreads();
    for (int off = 1; off < SCAN_B; off <<= 1) {
        int u = (t >= off) ? sh[t - off] : 0;
        __syncthreads();
        if (t >= off) sh[t] += u;
        __syncthreads();
    }
    int excl = sh[t] - v + boff[blockIdx.x];
    if (i < N3) {
        ptr[i]  = excl;
        fill[i] = excl;
    }
}

__global__ void k_build3(const int* __restrict__ e0, const int* __restrict__ e1,
                         const int* __restrict__ e2, int* __restrict__ fill,
                         int* __restrict__ adj) {
    int e = blockIdx.x * blockDim.x + threadIdx.x;
    if (e >= 3 * NE) return;
    int s = e / NE, r = e - s * NE;
    const int* ep = (s == 0 ? e0 : (s == 1 ? e1 : e2));
    int pos = atomicAdd(&fill[s * N_NODES + ep[NE + r]], 1);
    adj[pos] = ep[r];
}

// ---------------- split x (fp32) -> hi/lo bf16 planes ----------------

__global__ void k_split(const float* __restrict__ x, ushort* __restrict__ hi,
                        ushort* __restrict__ lo) {
    size_t i = ((size_t)blockIdx.x * 256 + threadIdx.x) * 4;
    if (i >= (size_t)N_NODES * H) return;
    float4 v = *(const float4*)(x + i);
    ushort4 h, l;
    h.x = f2bf(v.x); l.x = f2bf(v.x - bf2f(h.x));
    h.y = f2bf(v.y); l.y = f2bf(v.y - bf2f(h.y));
    h.z = f2bf(v.z); l.z = f2bf(v.z - bf2f(h.z));
    h.w = f2bf(v.w); l.w = f2bf(v.w - bf2f(h.w));
    *(ushort4*)(hi + i) = h;
    *(ushort4*)(lo + i) = l;
}

// ---------------- weight pre-scatter into MFMA fragment order (all 5 convs) ----------------
// B = [Wl | Wr]  (128 k x 256 n). k = q*32 + g*8 + j -> ((q*4+g)*256 + n)*8 + j.

__global__ void k_wsplit5(const float* W0l, const float* W0r, const float* W1l,
                          const float* W1r, const float* W2l, const float* W2r,
                          const float* W3l, const float* W3r, const float* W4l,
                          const float* W4r, ushort* __restrict__ Bpk) {
    int idx = blockIdx.x * 256 + threadIdx.x;  // 0..5*32768-1
    if (idx >= 5 * 32768) return;
    int c = idx >> 15, r = idx & 32767;
    const float* Wl = (c == 0 ? W0l : c == 1 ? W1l : c == 2 ? W2l : c == 3 ? W3l : W4l);
    const float* Wr = (c == 0 ? W0r : c == 1 ? W1r : c == 2 ? W2r : c == 3 ? W3r : W4r);
    int n = r & 255, k = r >> 8;
    float w = (n < H) ? Wl[k * H + n] : Wr[k * H + (n - H)];
    int q = k >> 5, g = (k >> 3) & 3, j = k & 7;
    int off = ((q * 4 + g) * 256 + n) * 8 + j;
    ushort h = f2bf(w);
    ushort* bh = Bpk + (size_t)c * 65536;
    bh[off]         = h;
    bh[32768 + off] = f2bf(w - bf2f(h));
}

// ---------------- MFMA GEMM: (z,y) = (Ahi+Alo) @ (Bhi+Blo) ----------------

__global__ __launch_bounds__(256) void k_gemm_mfma(
    const ushort* __restrict__ Ahi, const ushort* __restrict__ Alo,
    const ushort* __restrict__ Bh, const ushort* __restrict__ Bl,
    ushort* __restrict__ z, ushort* __restrict__ yb) {
    __shared__ ushort Ash[2][64][136];
    int t = threadIdx.x;
    int rowBase = blockIdx.x * 64;
    {
        int plane = t >> 7;
        int row   = (t >> 1) & 63;
        int half  = t & 1;
        const ushort* Ap = plane ? Alo : Ahi;
        int grow = rowBase + row;
        if (grow > N_NODES - 1) grow = N_NODES - 1;
        const int4* src = (const int4*)(Ap + (size_t)grow * H + half * 64);
        int4* dst = (int4*)&Ash[plane][row][half * 64];
#pragma unroll
        for (int i = 0; i < 8; ++i) dst[i] = src[i];
    }
    __syncthreads();

    int wave = t >> 6, lane = t & 63;
    int m16 = lane & 15, q4 = lane >> 4;
    int n0 = wave * 64;

    f32x4 acc[4][4];
#pragma unroll
    for (int r = 0; r < 4; ++r)
#pragma unroll
        for (int c = 0; c < 4; ++c) {
            acc[r][c][0] = 0.f; acc[r][c][1] = 0.f;
            acc[r][c][2] = 0.f; acc[r][c][3] = 0.f;
        }

    for (int q = 0; q < 4; ++q) {
        short8 bh_[4], bl_[4], ah_[4], al_[4];
#pragma unroll
        for (int c = 0; c < 4; ++c) {
            int boff = ((q * 4 + q4) * 256 + n0 + c * 16 + m16) * 8;
            bh_[c] = *(const short8*)(Bh + boff);
            bl_[c] = *(const short8*)(Bl + boff);
        }
#pragma unroll
        for (int r = 0; r < 4; ++r) {
            ah_[r] = *(const short8*)&Ash[0][r * 16 + m16][q * 32 + q4 * 8];
            al_[r] = *(const short8*)&Ash[1][r * 16 + m16][q * 32 + q4 * 8];
        }
#pragma unroll
        for (int r = 0; r < 4; ++r)
#pragma unroll
            for (int c = 0; c < 4; ++c) {
                acc[r][c] = __builtin_amdgcn_mfma_f32_16x16x32_bf16(
                    ah_[r], bh_[c], acc[r][c], 0, 0, 0);
                acc[r][c] = __builtin_amdgcn_mfma_f32_16x16x32_bf16(
                    ah_[r], bl_[c], acc[r][c], 0, 0, 0);
                acc[r][c] = __builtin_amdgcn_mfma_f32_16x16x32_bf16(
                    al_[r], bh_[c], acc[r][c], 0, 0, 0);
            }
    }

    // C/D layout: col=lane&15, row=(lane>>4)*4+reg (m89-verified)
#pragma unroll
    for (int r = 0; r < 4; ++r)
#pragma unroll
        for (int c = 0; c < 4; ++c) {
            int col = n0 + c * 16 + m16;
            ushort* op = (col < H) ? (z + col) : (yb + (col - H));
#pragma unroll
            for (int j = 0; j < 4; ++j) {
                int gr = rowBase + r * 16 + q4 * 4 + j;
                if (gr < N_NODES) op[(size_t)gr * H] = f2bf(acc[r][c][j]);
            }
        }
}

// ---------------- gather + epilogue (R6-PROVEN version) ----------------
// One 32-lane half-wave per node; ushort4 (8B)/lane covers the 256B bf16 row.
// Neighbor idx preloaded 32-wide, broadcast via shfl(width 32); 8-wide ILP.

__global__ __launch_bounds__(256) void k_aggnorm(
    const ushort* __restrict__ z, const ushort* __restrict__ yb,
    const int* __restrict__ ptr, const int* __restrict__ adj,
    const float* __restrict__ bl,
    ushort* __restrict__ hhi, ushort* __restrict__ hlo, int norm) {
    int wid  = (blockIdx.x * blockDim.x + threadIdx.x) >> 6;
    int lane = threadIdx.x & 63;
    int sl   = lane & 31;
    int node = wid * 2 + (lane >> 5);
    if (node >= N_NODES) return;
    int beg = ptr[node], end = ptr[node + 1];
    int deg = end - beg;
    const ushort* zrow = z + sl * 4;
    float a0 = 0.f, a1 = 0.f, a2 = 0.f, a3 = 0.f;
    for (int base = 0; base < deg; base += 32) {
        int m = deg - base;
        if (m > 32) m = 32;
        int idx = (sl < m) ? adj[beg + base + sl] : 0;
        int j = 0;
        for (; j + 8 <= m; j += 8) {
            int n0 = __shfl(idx, j,     32);
            int n1 = __shfl(idx, j + 1, 32);
            int n2 = __shfl(idx, j + 2, 32);
            int n3 = __shfl(idx, j + 3, 32);
            int n4 = __shfl(idx, j + 4, 32);
            int n5 = __shfl(idx, j + 5, 32);
            int n6 = __shfl(idx, j + 6, 32);
            int n7 = __shfl(idx, j + 7, 32);
            ushort4 v0 = *(const ushort4*)(zrow + (size_t)n0 * H);
            ushort4 v1 = *(const ushort4*)(zrow + (size_t)n1 * H);
            ushort4 v2 = *(const ushort4*)(zrow + (size_t)n2 * H);
            ushort4 v3 = *(const ushort4*)(zrow + (size_t)n3 * H);
            ushort4 v4 = *(const ushort4*)(zrow + (size_t)n4 * H);
            ushort4 v5 = *(const ushort4*)(zrow + (size_t)n5 * H);
            ushort4 v6 = *(const ushort4*)(zrow + (size_t)n6 * H);
            ushort4 v7 = *(const ushort4*)(zrow + (size_t)n7 * H);
            a0 += ((bf2f(v0.x) + bf2f(v1.x)) + (bf2f(v2.x) + bf2f(v3.x))) +
                  ((bf2f(v4.x) + bf2f(v5.x)) + (bf2f(v6.x) + bf2f(v7.x)));
            a1 += ((bf2f(v0.y) + bf2f(v1.y)) + (bf2f(v2.y) + bf2f(v3.y))) +
                  ((bf2f(v4.y) + bf2f(v5.y)) + (bf2f(v6.y) + bf2f(v7.y)));
            a2 += ((bf2f(v0.z) + bf2f(v1.z)) + (bf2f(v2.z) + bf2f(v3.z))) +
                  ((bf2f(v4.z) + bf2f(v5.z)) + (bf2f(v6.z) + bf2f(v7.z)));
            a3 += ((bf2f(v0.w) + bf2f(v1.w)) + (bf2f(v2.w) + bf2f(v3.w))) +
                  ((bf2f(v4.w) + bf2f(v5.w)) + (bf2f(v6.w) + bf2f(v7.w)));
        }
        for (; j + 4 <= m; j += 4) {
            int n0 = __shfl(idx, j,     32);
            int n1 = __shfl(idx, j + 1, 32);
            int n2 = __shfl(idx, j + 2, 32);
            int n3 = __shfl(idx, j + 3, 32);
            ushort4 v0 = *(const ushort4*)(zrow + (size_t)n0 * H);
            ushort4 v1 = *(const ushort4*)(zrow + (size_t)n1 * H);
            ushort4 v2 = *(const ushort4*)(zrow + (size_t)n2 * H);
            ushort4 v3 = *(const ushort4*)(zrow + (size_t)n3 * H);
            a0 += (bf2f(v0.x) + bf2f(v1.x)) + (bf2f(v2.x) + bf2f(v3.x));
            a1 += (bf2f(v0.y) + bf2f(v1.y)) + (bf2f(v2.y) + bf2f(v3.y));
            a2 += (bf2f(v0.z) + bf2f(v1.z)) + (bf2f(v2.z) + bf2f(v3.z));
            a3 += (bf2f(v0.w) + bf2f(v1.w)) + (bf2f(v2.w) + bf2f(v3.w));
        }
        for (; j < m; ++j) {
            int n0 = __shfl(idx, j, 32);
            ushort4 v0 = *(const ushort4*)(zrow + (size_t)n0 * H);
            a0 += bf2f(v0.x); a1 += bf2f(v0.y); a2 += bf2f(v0.z); a3 += bf2f(v0.w);
        }
    }
    float inv = 1.0f / (float)(deg > 1 ? deg : 1);
    ushort4 yv = *(const ushort4*)(yb + (size_t)node * H + sl * 4);
    float4 bv = *(const float4*)(bl + sl * 4);
    float v0 = a0 * inv + bv.x + bf2f(yv.x);
    float v1 = a1 * inv + bv.y + bf2f(yv.y);
    float v2 = a2 * inv + bv.z + bf2f(yv.z);
    float v3 = a3 * inv + bv.w + bf2f(yv.w);
    if (norm) {
        float ss = v0 * v0 + v1 * v1 + v2 * v2 + v3 * v3;
#pragma unroll
        for (int m = 1; m < 32; m <<= 1) ss += __shfl_xor(ss, m, 32);
        float n2 = 1.0f / fmaxf(sqrtf(ss), 1e-12f);
        v0 *= n2; v1 *= n2; v2 *= n2; v3 *= n2;
    }
    ushort4 h, l;
    h.x = f2bf(v0); l.x = f2bf(v0 - bf2f(h.x));
    h.y = f2bf(v1); l.y = f2bf(v1 - bf2f(h.y));
    h.z = f2bf(v2); l.z = f2bf(v2 - bf2f(h.z));
    h.w = f2bf(v3); l.w = f2bf(v3 - bf2f(h.w));
    *(ushort4*)(hhi + (size_t)node * H + sl * 4) = h;
    *(ushort4*)(hlo + (size_t)node * H + sl * 4) = l;
}

// ---------------- global add pool (batch sorted), h = hi + lo ----------------

constexpr int POOL_ROWS = 64;

__global__ void k_pool(const ushort* __restrict__ hhi, const ushort* __restrict__ hlo,
                       const int* __restrict__ batch, float* __restrict__ g) {
    int col = threadIdx.x;  // 0..127
    int r0 = blockIdx.x * POOL_ROWS;
    int r1 = r0 + POOL_ROWS;
    if (r1 > N_NODES) r1 = N_NODES;
    if (r0 >= N_NODES) return;
    float acc = 0.f;
    int cur = batch[r0];
    int r = r0;
    for (; r + 4 <= r1; r += 4) {
        float v0 = bf2f(hhi[(size_t)r * H + col])       + bf2f(hlo[(size_t)r * H + col]);
        float v1 = bf2f(hhi[(size_t)(r + 1) * H + col]) + bf2f(hlo[(size_t)(r + 1) * H + col]);
        float v2 = bf2f(hhi[(size_t)(r + 2) * H + col]) + bf2f(hlo[(size_t)(r + 2) * H + col]);
        float v3 = bf2f(hhi[(size_t)(r + 3) * H + col]) + bf2f(hlo[(size_t)(r + 3) * H + col]);
        int b3 = batch[r + 3];
        if (b3 == cur) {
            acc += (v0 + v1) + (v2 + v3);
        } else {
            int b0 = batch[r], b1 = batch[r + 1], b2 = batch[r + 2];
            if (b0 != cur) { atomicAdd(&g[cur * H + col], acc); acc = 0.f; cur = b0; }
            acc += v0;
            if (b1 != cur) { atomicAdd(&g[cur * H + col], acc); acc = 0.f; cur = b1; }
            acc += v1;
            if (b2 != cur) { atomicAdd(&g[cur * H + col], acc); acc = 0.f; cur = b2; }
            acc += v2;
            if (b3 != cur) { atomicAdd(&g[cur * H + col], acc); acc = 0.f; cur = b3; }
            acc += v3;
        }
    }
    for (; r < r1; ++r) {
        int b = batch[r];
        if (b != cur) { atomicAdd(&g[cur * H + col], acc); acc = 0.f; cur = b; }
        acc += bf2f(hhi[(size_t)r * H + col]) + bf2f(hlo[(size_t)r * H + col]);
    }
    atomicAdd(&g[cur * H + col], acc);
}

// ---------------- MLP head ----------------

__global__ void k_mlp(const float* __restrict__ g, const float* __restrict__ W0,
                      const float* __restrict__ b0, const float* __restrict__ W1,
                      const float* __restrict__ b1, const float* __restrict__ Wh,
                      const float* __restrict__ bh, float* __restrict__ out) {
    int gi = blockIdx.x;
    int t  = threadIdx.x;  // 0..127
    __shared__ float buf0[H];
    __shared__ float buf1[H];
    __shared__ float red[2];

    float acc = b0[t];
    for (int k = 0; k < H; ++k) acc += g[gi * H + k] * W0[k * H + t];
    buf0[t] = fmaxf(acc, 0.f);
    __syncthreads();

    acc = b1[t];
    for (int k = 0; k < H; ++k) acc += buf0[k] * W1[k * H + t];
    buf1[t] = fmaxf(acc, 0.f);
    __syncthreads();

    float p = buf1[t] * Wh[t];
    for (int m = 1; m < 64; m <<= 1) p += __shfl_xor(p, m, 64);
    if ((t & 63) == 0) red[t >> 6] = p;
    __syncthreads();
    if (t == 0) out[gi] = red[0] + red[1] + bh[0];
}

// ---------------- driver ----------------

extern "C" void kernel_launch(void* const* d_in, const int* in_sizes, int n_in,
                              void* d_out, int out_size, void* d_ws, size_t ws_size,
                              hipStream_t stream) {
    const float* x     = (const float*)d_in[0];
    const int*   eic   = (const int*)d_in[1];
    const int*   eid   = (const int*)d_in[2];
    const int*   eit   = (const int*)d_in[3];
    const int*   batch = (const int*)d_in[4];
    const float* cW[5][3];
    for (int c = 0; c < 5; ++c) {
        cW[c][0] = (const float*)d_in[5 + c * 3 + 0];  // Wl
        cW[c][1] = (const float*)d_in[5 + c * 3 + 1];  // bl
        cW[c][2] = (const float*)d_in[5 + c * 3 + 2];  // Wr
    }
    const float* l0_W = (const float*)d_in[20];
    const float* l0_b = (const float*)d_in[21];
    const float* l1_W = (const float*)d_in[22];
    const float* l1_b = (const float*)d_in[23];
    const float* hd_W = (const float*)d_in[24];
    const float* hd_b = (const float*)d_in[25];
    float* outp = (float*)d_out;

    const size_t NH = (size_t)N_NODES * H;
    ushort* Ahi = (ushort*)d_ws;
    ushort* Alo = Ahi + NH;
    ushort* zb  = Alo + NH;
    ushort* yb  = zb + NH;
    ushort* Bpk = yb + NH;                     // 5 convs x 2 planes x 32768
    float*  gbuf = (float*)(Bpk + 5 * 2 * 32768);
    int* ptr_all = (int*)(gbuf + (size_t)NG * H);  // N3+1 ints (persistent)
    int* adj_all = ptr_all + (N3 + 1);             // 3*NE ints (persistent)
    // CSR-build scratch inside zb (600KB + 2.4KB << 12.8MB; dead before gemm 0)
    int* fill = (int*)zb;                          // N3 ints (counts, then fill)
    int* bsum = fill + N3;                         // SCAN_G3 ints

    dim3 b256(256);
    dim3 gE3((3 * NE + 255) / 256);

    // weight pre-scatter + x split
    k_wsplit5<<<dim3(640), b256, 0, stream>>>(cW[0][0], cW[0][2], cW[1][0], cW[1][2],
                                              cW[2][0], cW[2][2], cW[3][0], cW[3][2],
                                              cW[4][0], cW[4][2], Bpk);
    k_split<<<dim3((int)(NH / 1024)), b256, 0, stream>>>(x, Ahi, Alo);

    // build all 3 CSRs in one pass (dst-sorted, combined adj space)
    hipMemsetAsync(fill, 0, N3 * sizeof(int), stream);
    k_count3<<<gE3, b256, 0, stream>>>(eic, eid, eit, fill);
    k_bsum<<<dim3(SCAN_G3), b256, 0, stream>>>(fill, bsum);
    k_bscan<<<dim3(1), dim3(1024), 0, stream>>>(bsum, ptr_all);
    k_bwrite<<<dim3(SCAN_G3), b256, 0, stream>>>(fill, bsum, ptr_all, fill);
    k_build3<<<gE3, b256, 0, stream>>>(eic, eid, eit, fill, adj_all);

    const int L_set[7]  = {1, 0, 0, 2, 1, 0, 0};
    const int L_conv[7] = {0, 1, 1, 2, 3, 4, 4};
    const int L_norm[7] = {1, 1, 1, 0, 1, 1, 1};

    int nWaves = (N_NODES + 1) / 2;          // 2 nodes per wave (R6-proven)
    dim3 gAgg((nWaves + 3) / 4);             // 4 waves/block
    dim3 gGemm((N_NODES + 63) / 64);         // 782

    for (int L = 0; L < 7; ++L) {
        int s = L_set[L], c = L_conv[L];
        const ushort* Bh = Bpk + (size_t)c * 65536;
        const ushort* Bl = Bh + 32768;
        k_gemm_mfma<<<gGemm, b256, 0, stream>>>(Ahi, Alo, Bh, Bl, zb, yb);
        k_aggnorm<<<gAgg, b256, 0, stream>>>(zb, yb, ptr_all + s * N_NODES, adj_all,
                                             cW[c][1], Ahi, Alo, L_norm[L]);
    }

    hipMemsetAsync(gbuf, 0, (size_t)NG * H * sizeof(float), stream);
    k_pool<<<dim3((N_NODES + POOL_ROWS - 1) / POOL_ROWS), dim3(H), 0, stream>>>(
        Ahi, Alo, batch, gbuf);
    k_mlp<<<dim3(NG), dim3(H), 0, stream>>>(gbuf, l0_W, l0_b, l1_W, l1_b, hd_W, hd_b,
                                            outp);
}